// Round 2
// baseline (944.652 us; speedup 1.0000x reference)
//
#include <hip/hip_runtime.h>

#define V 86
#define CIN 64
#define COUT 128
#define BT 8192            // 32*256
#define NSTAT (32*256*86)  // 704512

// workspace offsets (bytes)
#define OFF_FLAG  0        // int: 1 = bf16 tensors, 0 = float32 tensors
#define OFF_CNT   512      // int[86]
#define OFF_NBRV  1024     // int[86*96]
#define OFF_NBRW  34048    // float[86*96]
#define OFF_WT    67072    // ushort[128*64]  (w transposed, [d][c], bf16)
#define OFF_GSUM  83456    // float[128]
#define OFF_GSQ   83968    // float[128]
#define OFF_SCALE 84480    // float[128]
#define OFF_SHIFT 84992    // float[128]

typedef short short8 __attribute__((ext_vector_type(8)));
typedef float float4v __attribute__((ext_vector_type(4)));

static __device__ __forceinline__ float bf2f(ushort u) {
    union { uint i; float f; } c; c.i = ((uint)u) << 16; return c.f;
}
static __device__ __forceinline__ ushort f2bf(float f) {
    union { float f; uint i; } c; c.f = f;
    uint u = c.i;
    uint r = u + 0x7FFFu + ((u >> 16) & 1u);   // RNE
    return (ushort)(r >> 16);
}
static __device__ __forceinline__ uint packbf(float a, float b) {
    return (uint)f2bf(a) | ((uint)f2bf(b) << 16);
}
// generic scalar load -> float
template<bool BF>
static __device__ __forceinline__ float ldg(const void* p, int i) {
    if (BF) return bf2f(((const ushort*)p)[i]);
    else    return ((const float*)p)[i];
}

// ---------------- K0: detect tensor dtype from adj bit patterns ----------------
// f32 0/1 adjacency: every 32b word is 0x00000000 or 0x3F800000.
// bf16 adjacency: words 0x00003F80 (pair [1,0]) / 0x3F803F80 (pair [1,1]) occur
// with overwhelming probability (~590 ones in 7396 elems) and are impossible for f32.
__global__ void k0_detect(const uint* __restrict__ adj_raw, char* __restrict__ ws) {
    __shared__ int s_found;
    if (threadIdx.x == 0) s_found = 0;
    __syncthreads();
    int found = 0;
    for (int i = threadIdx.x; i < 3698; i += blockDim.x) {  // 3698 = bf16 word count (safe for f32 too)
        uint wd = adj_raw[i];
        if (wd == 0x00003F80u || wd == 0x3F803F80u) found = 1;
    }
    if (found) atomicOr(&s_found, 1);
    __syncthreads();
    if (threadIdx.x == 0) *(int*)(ws + OFF_FLAG) = s_found;
}

// ---------------- K1: norm_adj CSR + wT + zero stats ----------------
template<bool BF>
__global__ void k1_prep(const void* __restrict__ adj, const void* __restrict__ w,
                        char* __restrict__ ws) {
    const int flag = *(const volatile int*)(ws + OFF_FLAG);
    if ((flag != 0) != BF) return;
    __shared__ float dinv[V];
    int t = threadIdx.x;
    int*    cnt  = (int*)(ws + OFF_CNT);
    int*    nbrv = (int*)(ws + OFF_NBRV);
    float*  nbrw = (float*)(ws + OFF_NBRW);
    ushort* wT   = (ushort*)(ws + OFF_WT);
    float*  gsum = (float*)(ws + OFF_GSUM);
    float*  gsq  = (float*)(ws + OFF_GSQ);

    if (t < V) {
        float s = 0.f;
        for (int v2 = 0; v2 < V; ++v2)
            s += ldg<BF>(adj, t * V + v2) + (v2 == t ? 1.f : 0.f);
        dinv[t] = rsqrtf(s);
    }
    __syncthreads();
    if (t < V) {
        int c = 0;
        float du = dinv[t];
        for (int v2 = 0; v2 < V; ++v2) {
            float a = ldg<BF>(adj, t * V + v2) + (v2 == t ? 1.f : 0.f);
            if (a != 0.f) {
                nbrv[t * 96 + c] = v2;
                nbrw[t * 96 + c] = du * a * dinv[v2];
                ++c;
            }
        }
        cnt[t] = c;
    }
    // transpose w [c][d] -> wT [d][c], as bf16
    for (int i = t; i < CIN * COUT; i += blockDim.x) {
        int cc = i >> 7, d = i & 127;
        wT[d * CIN + cc] = BF ? ((const ushort*)w)[i] : f2bf(((const float*)w)[i]);
    }
    if (t < COUT) { gsum[t] = 0.f; gsq[t] = 0.f; }
}

// ---------------- K2: per-bt aggregation (sparse VALU) + agg@w (MFMA) + stats ----------------
#define XS_STRIDE 68
#define AG_STRIDE 72
#define ZS_STRIDE 136
#define SMEMA_SH (V * XS_STRIDE + 96 * AG_STRIDE)   // 12760 shorts = 25520 B

template<bool BF>
__global__ __launch_bounds__(256) void k2_main(const void* __restrict__ x,
                                               char* __restrict__ ws,
                                               void* __restrict__ zout) {
    const int flag = *(const volatile int*)(ws + OFF_FLAG);
    if ((flag != 0) != BF) return;
    __shared__ __align__(16) short smemA[SMEMA_SH];
    __shared__ __align__(16) short smemW[COUT * AG_STRIDE];  // 18432 B
    __shared__ float s_sum[COUT], s_sq[COUT];

    const int*    cnt  = (const int*)(ws + OFF_CNT);
    const int*    nbrv = (const int*)(ws + OFF_NBRV);
    const float*  nbrw = (const float*)(ws + OFF_NBRW);
    const ushort* wT   = (const ushort*)(ws + OFF_WT);
    float* gsum = (float*)(ws + OFF_GSUM);
    float* gsq  = (float*)(ws + OFF_GSQ);

    const int tid  = threadIdx.x;
    const int lane = tid & 63, wv = tid >> 6;
    const int col  = lane & 15, quad = lane >> 4;
    const int colg = tid & 15, rowb = tid >> 4;

    for (int i = tid; i < COUT * 8; i += 256) {   // wT -> LDS, 1024 x uint4
        int n = i >> 3, j = i & 7;
        *(uint4*)&smemW[n * AG_STRIDE + j * 8] = *(const uint4*)&wT[n * CIN + j * 8];
    }
    if (tid < COUT) { s_sum[tid] = 0.f; s_sq[tid] = 0.f; }

    float ssum[8] = {0.f,0.f,0.f,0.f,0.f,0.f,0.f,0.f};
    float ssq[8]  = {0.f,0.f,0.f,0.f,0.f,0.f,0.f,0.f};

    for (int ib = 0; ib < 4; ++ib) {
        const int bt = blockIdx.x * 4 + ib;
        __syncthreads();   // region A reuse barrier

        // ---- load x slice into LDS (as bf16) ----
        if (BF) {
            const ushort* xg = (const ushort*)x + (size_t)bt * (V * CIN);
            for (int i = tid; i < V * 16; i += 256) {
                int r = i >> 4, c4 = i & 15;
                *(uint2*)&smemA[r * XS_STRIDE + c4 * 4] = *(const uint2*)&xg[r * CIN + c4 * 4];
            }
        } else {
            const float* xg = (const float*)x + (size_t)bt * (V * CIN);
            for (int i = tid; i < V * 16; i += 256) {
                int r = i >> 4, c4 = i & 15;
                float4 f = *(const float4*)&xg[r * CIN + c4 * 4];
                uint2 o; o.x = packbf(f.x, f.y); o.y = packbf(f.z, f.w);
                *(uint2*)&smemA[r * XS_STRIDE + c4 * 4] = o;
            }
        }
        __syncthreads();

        // ---- stage 1: sparse aggregation ----
        short* s_agg = smemA + V * XS_STRIDE;
        for (int it = 0; it < 6; ++it) {
            int item = tid + it * 256;       // 1536 = 96 u x 16 cgroups
            int u = item >> 4, cg = item & 15;
            float a0 = 0.f, a1 = 0.f, a2 = 0.f, a3 = 0.f;
            int c = (u < V) ? cnt[u] : 0;
            const int*   vp = nbrv + u * 96;
            const float* wp = nbrw + u * 96;
            for (int j = 0; j < c; ++j) {
                int v2 = vp[j];
                float wg = wp[j];
                uint2 p = *(const uint2*)&smemA[v2 * XS_STRIDE + cg * 4];
                a0 += wg * bf2f((ushort)(p.x & 0xffffu));
                a1 += wg * bf2f((ushort)(p.x >> 16));
                a2 += wg * bf2f((ushort)(p.y & 0xffffu));
                a3 += wg * bf2f((ushort)(p.y >> 16));
            }
            uint2 o; o.x = packbf(a0, a1); o.y = packbf(a2, a3);
            *(uint2*)&s_agg[u * AG_STRIDE + cg * 4] = o;
        }
        __syncthreads();

        // ---- stage 2: z = agg @ w via MFMA 16x16x32 bf16 ----
        float4v acc[2][6];
        #pragma unroll
        for (int a = 0; a < 2; ++a)
            #pragma unroll
            for (int m = 0; m < 6; ++m)
                acc[a][m] = (float4v){0.f, 0.f, 0.f, 0.f};

        #pragma unroll
        for (int ks = 0; ks < 2; ++ks) {
            const int k0 = quad * 8 + ks * 32;
            short8 af[6];
            #pragma unroll
            for (int m = 0; m < 6; ++m)
                af[m] = *(const short8*)&s_agg[(m * 16 + col) * AG_STRIDE + k0];
            #pragma unroll
            for (int ndl = 0; ndl < 2; ++ndl) {
                const int n = (wv * 2 + ndl) * 16 + col;
                short8 bfr = *(const short8*)&smemW[n * AG_STRIDE + k0];
                #pragma unroll
                for (int m = 0; m < 6; ++m)
                    acc[ndl][m] = __builtin_amdgcn_mfma_f32_16x16x32_bf16(af[m], bfr, acc[ndl][m], 0, 0, 0);
            }
        }
        __syncthreads();   // s_x / s_agg dead -> reuse as s_z

        // ---- stage z tile into LDS (D layout: row = quad*4+r, col = lane&15) ----
        short* s_z = smemA;
        #pragma unroll
        for (int ndl = 0; ndl < 2; ++ndl) {
            const int n = (wv * 2 + ndl) * 16 + col;
            #pragma unroll
            for (int m = 0; m < 6; ++m) {
                #pragma unroll
                for (int r = 0; r < 4; ++r) {
                    int row = m * 16 + quad * 4 + r;
                    if (row < V) s_z[row * ZS_STRIDE + n] = (short)f2bf(acc[ndl][m][r]);
                }
            }
        }
        __syncthreads();

        // ---- coalesced copy-out + register stats ----
        for (int it = 0; it < 6; ++it) {
            int row = rowb + it * 16;
            if (row < V) {
                uint4 val = *(const uint4*)&s_z[row * ZS_STRIDE + colg * 8];
                uint vv[4] = {val.x, val.y, val.z, val.w};
                float f[8];
                #pragma unroll
                for (int q = 0; q < 4; ++q) {
                    f[2 * q]     = bf2f((ushort)(vv[q] & 0xffffu));
                    f[2 * q + 1] = bf2f((ushort)(vv[q] >> 16));
                }
                if (BF) {
                    ushort* zg = (ushort*)zout + (size_t)bt * (V * COUT);
                    *(uint4*)&zg[row * COUT + colg * 8] = val;
                } else {
                    float* zg = (float*)zout + (size_t)bt * (V * COUT);
                    float4 a; a.x = f[0]; a.y = f[1]; a.z = f[2]; a.w = f[3];
                    float4 b; b.x = f[4]; b.y = f[5]; b.z = f[6]; b.w = f[7];
                    *(float4*)&zg[row * COUT + colg * 8]     = a;
                    *(float4*)&zg[row * COUT + colg * 8 + 4] = b;
                }
                #pragma unroll
                for (int k = 0; k < 8; ++k) { ssum[k] += f[k]; ssq[k] += f[k] * f[k]; }
            }
        }
    }
    __syncthreads();
    #pragma unroll
    for (int k = 0; k < 8; ++k) {
        atomicAdd(&s_sum[colg * 8 + k], ssum[k]);
        atomicAdd(&s_sq[colg * 8 + k],  ssq[k]);
    }
    __syncthreads();
    if (tid < COUT) {
        atomicAdd(&gsum[tid], s_sum[tid]);
        atomicAdd(&gsq[tid],  s_sq[tid]);
    }
}

// ---------------- K3: finalize BN scale/shift ----------------
template<bool BF>
__global__ void k3_finalize(const void* __restrict__ gamma, const void* __restrict__ beta,
                            char* __restrict__ ws) {
    const int flag = *(const volatile int*)(ws + OFF_FLAG);
    if ((flag != 0) != BF) return;
    int d = threadIdx.x;
    if (d < COUT) {
        const float* gsum = (const float*)(ws + OFF_GSUM);
        const float* gsq  = (const float*)(ws + OFF_GSQ);
        float* scale = (float*)(ws + OFF_SCALE);
        float* shift = (float*)(ws + OFF_SHIFT);
        const float inv_n = 1.f / (float)NSTAT;
        float mean = gsum[d] * inv_n;
        float var  = gsq[d] * inv_n - mean * mean;
        float sc   = ldg<BF>(gamma, d) * rsqrtf(var + 1e-5f);
        scale[d] = sc;
        shift[d] = ldg<BF>(beta, d) - mean * sc;
    }
}

// ---------------- K4: in-place BN apply + ReLU ----------------
template<bool BF>
__global__ __launch_bounds__(256) void k4_bn_relu(void* __restrict__ z,
                                                  char* __restrict__ ws) {
    const int flag = *(const volatile int*)(ws + OFF_FLAG);
    if ((flag != 0) != BF) return;
    __shared__ float s_scale[COUT], s_shift[COUT];
    const int tid = threadIdx.x;
    if (tid < COUT) {
        s_scale[tid] = ((const float*)(ws + OFF_SCALE))[tid];
        s_shift[tid] = ((const float*)(ws + OFF_SHIFT))[tid];
    }
    __syncthreads();
    const long long stride = (long long)gridDim.x * blockDim.x;
    if (BF) {
        const long long NVEC = (long long)BT * V * COUT / 8;  // uint4 = 8 bf16
        for (long long i = (long long)blockIdx.x * blockDim.x + tid; i < NVEC; i += stride) {
            uint4 val = *((const uint4*)z + i);
            int d0 = ((int)(i & 15)) * 8;
            uint vv[4] = {val.x, val.y, val.z, val.w};
            uint ov[4];
            #pragma unroll
            for (int q = 0; q < 4; ++q) {
                float f0 = bf2f((ushort)(vv[q] & 0xffffu)) * s_scale[d0 + 2 * q]     + s_shift[d0 + 2 * q];
                float f1 = bf2f((ushort)(vv[q] >> 16))     * s_scale[d0 + 2 * q + 1] + s_shift[d0 + 2 * q + 1];
                ov[q] = packbf(fmaxf(f0, 0.f), fmaxf(f1, 0.f));
            }
            uint4 o; o.x = ov[0]; o.y = ov[1]; o.z = ov[2]; o.w = ov[3];
            *((uint4*)z + i) = o;
        }
    } else {
        const long long NVEC = (long long)BT * V * COUT / 4;  // float4
        float4* zf = (float4*)z;
        for (long long i = (long long)blockIdx.x * blockDim.x + tid; i < NVEC; i += stride) {
            float4 v = zf[i];
            int d0 = ((int)(i & 31)) * 4;
            v.x = fmaxf(v.x * s_scale[d0]     + s_shift[d0],     0.f);
            v.y = fmaxf(v.y * s_scale[d0 + 1] + s_shift[d0 + 1], 0.f);
            v.z = fmaxf(v.z * s_scale[d0 + 2] + s_shift[d0 + 2], 0.f);
            v.w = fmaxf(v.w * s_scale[d0 + 3] + s_shift[d0 + 3], 0.f);
            zf[i] = v;
        }
    }
}

extern "C" void kernel_launch(void* const* d_in, const int* in_sizes, int n_in,
                              void* d_out, int out_size, void* d_ws, size_t ws_size,
                              hipStream_t stream) {
    const void* x     = d_in[0];
    const void* adj   = d_in[1];
    const void* w     = d_in[2];
    const void* gamma = d_in[3];
    const void* beta  = d_in[4];
    char* ws = (char*)d_ws;

    hipLaunchKernelGGL(k0_detect, dim3(1), dim3(256), 0, stream, (const uint*)adj, ws);
    hipLaunchKernelGGL((k1_prep<true>),     dim3(1),    dim3(128), 0, stream, adj, w, ws);
    hipLaunchKernelGGL((k1_prep<false>),    dim3(1),    dim3(128), 0, stream, adj, w, ws);
    hipLaunchKernelGGL((k2_main<true>),     dim3(2048), dim3(256), 0, stream, x, ws, d_out);
    hipLaunchKernelGGL((k2_main<false>),    dim3(2048), dim3(256), 0, stream, x, ws, d_out);
    hipLaunchKernelGGL((k3_finalize<true>), dim3(1),    dim3(128), 0, stream, gamma, beta, ws);
    hipLaunchKernelGGL((k3_finalize<false>),dim3(1),    dim3(128), 0, stream, gamma, beta, ws);
    hipLaunchKernelGGL((k4_bn_relu<true>),  dim3(4096), dim3(256), 0, stream, d_out, ws);
    hipLaunchKernelGGL((k4_bn_relu<false>), dim3(4096), dim3(256), 0, stream, d_out, ws);
}

// Round 3
// 612.879 us; speedup vs baseline: 1.5413x; 1.5413x over previous
//
#include <hip/hip_runtime.h>

#define V 86
#define VP 96              // padded vertex count
#define CIN 64
#define COUT 128
#define BT 8192            // 32*256
#define NSTAT (32*256*86)  // 704512

// workspace offsets (bytes)
#define OFF_FLAG  0        // int: 1 = bf16 tensors, 0 = float32 tensors
#define OFF_NADJ  512      // bf16 [96][96] zero-padded norm_adj (18432 B)
#define OFF_WT    19456    // bf16 [128][64] w transposed [d][c] (16384 B)
#define OFF_GSUM  35840    // float[128]
#define OFF_GSQ   36352    // float[128]
#define OFF_SCALE 36864    // float[128]
#define OFF_SHIFT 37376    // float[128]

typedef short short8 __attribute__((ext_vector_type(8)));
typedef float float4v __attribute__((ext_vector_type(4)));

static __device__ __forceinline__ float bf2f(ushort u) {
    union { uint i; float f; } c; c.i = ((uint)u) << 16; return c.f;
}
static __device__ __forceinline__ ushort f2bf(float f) {
    union { float f; uint i; } c; c.f = f;
    uint u = c.i;
    uint r = u + 0x7FFFu + ((u >> 16) & 1u);   // RNE
    return (ushort)(r >> 16);
}
static __device__ __forceinline__ uint packbf(float a, float b) {
    return (uint)f2bf(a) | ((uint)f2bf(b) << 16);
}
template<bool BF>
static __device__ __forceinline__ float ldg(const void* p, int i) {
    if (BF) return bf2f(((const ushort*)p)[i]);
    else    return ((const float*)p)[i];
}

// ---------------- K0: detect tensor dtype from adj bit patterns ----------------
// f32 0/1 adjacency: every 32b word is 0x00000000 or 0x3F800000.
// bf16 adjacency: words 0x00003F80 / 0x3F803F80 occur w.h.p. and are impossible for f32.
__global__ void k0_detect(const uint* __restrict__ adj_raw, char* __restrict__ ws) {
    __shared__ int s_found;
    if (threadIdx.x == 0) s_found = 0;
    __syncthreads();
    int found = 0;
    for (int i = threadIdx.x; i < 3698; i += blockDim.x) {
        uint wd = adj_raw[i];
        if (wd == 0x00003F80u || wd == 0x3F803F80u) found = 1;
    }
    if (found) atomicOr(&s_found, 1);
    __syncthreads();
    if (threadIdx.x == 0) *(int*)(ws + OFF_FLAG) = s_found;
}

// ---------------- K1: dense padded norm_adj (bf16) + wT + zero stats ----------------
template<bool BF>
__global__ void k1_prep(const void* __restrict__ adj, const void* __restrict__ w,
                        char* __restrict__ ws) {
    const int flag = *(const volatile int*)(ws + OFF_FLAG);
    if ((flag != 0) != BF) return;
    __shared__ float dinv[V];
    const int t = threadIdx.x;
    ushort* nadj = (ushort*)(ws + OFF_NADJ);
    ushort* wT   = (ushort*)(ws + OFF_WT);
    float*  gsum = (float*)(ws + OFF_GSUM);
    float*  gsq  = (float*)(ws + OFF_GSQ);

    if (t < V) {
        float s = 0.f;
        for (int v2 = 0; v2 < V; ++v2)
            s += ldg<BF>(adj, t * V + v2) + (v2 == t ? 1.f : 0.f);
        dinv[t] = rsqrtf(s);
    }
    __syncthreads();
    // dense padded nadj[u][v] = dinv[u]*(a+I)*dinv[v], zero for u,v >= 86
    for (int i = t; i < VP * VP; i += blockDim.x) {
        int u = i / VP, v2 = i % VP;
        float val = 0.f;
        if (u < V && v2 < V) {
            float a = ldg<BF>(adj, u * V + v2) + (v2 == u ? 1.f : 0.f);
            val = dinv[u] * a * dinv[v2];
        }
        nadj[i] = f2bf(val);
    }
    // w [c][d] -> wT [d][c] bf16
    for (int i = t; i < CIN * COUT; i += blockDim.x) {
        int cc = i >> 7, d = i & 127;
        wT[d * CIN + cc] = BF ? ((const ushort*)w)[i] : f2bf(((const float*)w)[i]);
    }
    if (t < COUT) { gsum[t] = 0.f; gsq[t] = 0.f; }
}

// ---------------- K2 pass: z = nadj @ (x @ w), all-MFMA, 8 bt per block ----------------
// STATS=false: apply BN scale/shift + ReLU, store out. STATS=true: accumulate sum/sumsq only.
#define NJ_STR 104   // shorts; 208 B rows: 16B-aligned, 2-way bank alias only
#define XS_STR 72    // 144 B rows
#define YT_STR 104

template<bool BF, bool STATS>
__global__ __launch_bounds__(512, 4) void k2_pass(const void* __restrict__ x,
                                                  char* __restrict__ ws,
                                                  void* __restrict__ outv) {
    const int flag = *(const volatile int*)(ws + OFF_FLAG);
    if ((flag != 0) != BF) return;

    __shared__ __align__(16) short s_nadj[VP * NJ_STR];   // 19968 B
    __shared__ __align__(16) short s_x[VP * XS_STR];      // 13824 B
    __shared__ __align__(16) short s_yT[COUT * YT_STR];   // 26624 B

    const int tid  = threadIdx.x;
    const int lane = tid & 63, wv = tid >> 6;     // 8 waves
    const int col  = lane & 15, quad = lane >> 4;
    const int d_own = wv * 16 + col;              // this lane's output channel

    // nadj -> LDS once per block (global [96][96] -> [96][104])
    {
        const ushort* g = (const ushort*)(ws + OFF_NADJ);
        for (int i = tid; i < VP * 12; i += 512) {   // 12 x uint4 (8 shorts) per row
            int r = i / 12, j = i % 12;
            *(uint4*)&s_nadj[r * NJ_STR + j * 8] = *(const uint4*)&g[r * VP + j * 8];
        }
    }
    // w B-fragments live in registers for the whole kernel
    short8 bw[2];
    {
        const ushort* wt = (const ushort*)(ws + OFF_WT);
        bw[0] = *(const short8*)&wt[d_own * CIN + quad * 8];
        bw[1] = *(const short8*)&wt[d_own * CIN + 32 + quad * 8];
    }
    // zero-pad x rows 86..95 (written once; x loads only touch rows < 86)
    if (tid < 160) {
        int r = V + (tid >> 4), j = tid & 15;
        *(uint2*)&s_x[r * XS_STR + j * 4] = (uint2){0u, 0u};
    }
    float sc = 0.f, sh = 0.f;
    if (!STATS) {
        sc = ((const float*)(ws + OFF_SCALE))[d_own];
        sh = ((const float*)(ws + OFF_SHIFT))[d_own];
    }
    float s1 = 0.f, s2 = 0.f;

    for (int ib = 0; ib < 8; ++ib) {
        const int bt = blockIdx.x * 8 + ib;
        __syncthreads();   // guards s_x / s_yT reuse across iterations

        // ---- x slice -> LDS bf16 [86][64] ----
        if (BF) {
            const ushort* xg = (const ushort*)x + (size_t)bt * (V * CIN);
            for (int i = tid; i < V * 8; i += 512) {     // 688 x uint4
                int r = i >> 3, j = i & 7;
                *(uint4*)&s_x[r * XS_STR + j * 8] = *(const uint4*)&xg[r * CIN + j * 8];
            }
        } else {
            const float* xg = (const float*)x + (size_t)bt * (V * CIN);
            for (int i = tid; i < V * 16; i += 512) {    // 1376 x float4 -> uint2
                int r = i >> 4, j = i & 15;
                float4 f = *(const float4*)&xg[r * CIN + j * 4];
                uint2 o; o.x = packbf(f.x, f.y); o.y = packbf(f.z, f.w);
                *(uint2*)&s_x[r * XS_STR + j * 4] = o;
            }
        }
        __syncthreads();

        // ---- stage A: y = x @ w  (M=96 rows v, N=16 own d-tile, K=64) ----
        float4v accy[6];
        #pragma unroll
        for (int m = 0; m < 6; ++m) accy[m] = (float4v){0.f, 0.f, 0.f, 0.f};
        #pragma unroll
        for (int ks = 0; ks < 2; ++ks) {
            #pragma unroll
            for (int m = 0; m < 6; ++m) {
                short8 ax = *(const short8*)&s_x[(m * 16 + col) * XS_STR + ks * 32 + quad * 8];
                accy[m] = __builtin_amdgcn_mfma_f32_16x16x32_bf16(ax, bw[ks], accy[m], 0, 0, 0);
            }
        }
        // y D-frags -> yT[d][v] (transposed so stage-B B-frags are k-contiguous)
        #pragma unroll
        for (int m = 0; m < 6; ++m)
            #pragma unroll
            for (int r = 0; r < 4; ++r)
                s_yT[d_own * YT_STR + m * 16 + quad * 4 + r] = (short)f2bf(accy[m][r]);
        __syncthreads();

        // ---- stage B: z = nadj @ y  (M=96 rows u, N=16 own d-tile, K=96) ----
        float4v accz[6];
        #pragma unroll
        for (int m = 0; m < 6; ++m) accz[m] = (float4v){0.f, 0.f, 0.f, 0.f};
        #pragma unroll
        for (int ks = 0; ks < 3; ++ks) {
            short8 by = *(const short8*)&s_yT[d_own * YT_STR + ks * 32 + quad * 8];
            #pragma unroll
            for (int m = 0; m < 6; ++m) {
                short8 an = *(const short8*)&s_nadj[(m * 16 + col) * NJ_STR + ks * 32 + quad * 8];
                accz[m] = __builtin_amdgcn_mfma_f32_16x16x32_bf16(an, by, accz[m], 0, 0, 0);
            }
        }

        // ---- epilogue: stats or BN+ReLU+store (D-frag: row u = m*16+quad*4+r, col d_own) ----
        if (STATS) {
            #pragma unroll
            for (int m = 0; m < 6; ++m)
                #pragma unroll
                for (int r = 0; r < 4; ++r) {
                    int u = m * 16 + quad * 4 + r;
                    if (u < V) { float v2 = accz[m][r]; s1 += v2; s2 += v2 * v2; }
                }
        } else {
            const size_t base = (size_t)bt * (V * COUT) + d_own;
            #pragma unroll
            for (int m = 0; m < 6; ++m)
                #pragma unroll
                for (int r = 0; r < 4; ++r) {
                    int u = m * 16 + quad * 4 + r;
                    if (u < V) {
                        float val = fmaxf(accz[m][r] * sc + sh, 0.f);
                        if (BF) ((ushort*)outv)[base + (size_t)u * COUT] = f2bf(val);
                        else    ((float*)outv)[base + (size_t)u * COUT]  = val;
                    }
                }
        }
    }

    if (STATS) {
        // reduce over the 4 quads sharing d_own, then one atomic per channel per block
        s1 += __shfl_xor(s1, 16); s1 += __shfl_xor(s1, 32);
        s2 += __shfl_xor(s2, 16); s2 += __shfl_xor(s2, 32);
        if (quad == 0) {
            atomicAdd((float*)(ws + OFF_GSUM) + d_own, s1);
            atomicAdd((float*)(ws + OFF_GSQ)  + d_own, s2);
        }
    }
}

// ---------------- K3: finalize BN scale/shift ----------------
template<bool BF>
__global__ void k3_finalize(const void* __restrict__ gamma, const void* __restrict__ beta,
                            char* __restrict__ ws) {
    const int flag = *(const volatile int*)(ws + OFF_FLAG);
    if ((flag != 0) != BF) return;
    int d = threadIdx.x;
    if (d < COUT) {
        const float* gsum = (const float*)(ws + OFF_GSUM);
        const float* gsq  = (const float*)(ws + OFF_GSQ);
        float* scale = (float*)(ws + OFF_SCALE);
        float* shift = (float*)(ws + OFF_SHIFT);
        const float inv_n = 1.f / (float)NSTAT;
        float mean = gsum[d] * inv_n;
        float var  = gsq[d] * inv_n - mean * mean;
        float s    = ldg<BF>(gamma, d) * rsqrtf(var + 1e-5f);
        scale[d] = s;
        shift[d] = ldg<BF>(beta, d) - mean * s;
    }
}

extern "C" void kernel_launch(void* const* d_in, const int* in_sizes, int n_in,
                              void* d_out, int out_size, void* d_ws, size_t ws_size,
                              hipStream_t stream) {
    const void* x     = d_in[0];
    const void* adj   = d_in[1];
    const void* w     = d_in[2];
    const void* gamma = d_in[3];
    const void* beta  = d_in[4];
    char* ws = (char*)d_ws;

    hipLaunchKernelGGL(k0_detect, dim3(1), dim3(256), 0, stream, (const uint*)adj, ws);
    hipLaunchKernelGGL((k1_prep<true>),  dim3(1), dim3(256), 0, stream, adj, w, ws);
    hipLaunchKernelGGL((k1_prep<false>), dim3(1), dim3(256), 0, stream, adj, w, ws);
    // stats pass (no z write)
    hipLaunchKernelGGL((k2_pass<true,  true>),  dim3(1024), dim3(512), 0, stream, x, ws, d_out);
    hipLaunchKernelGGL((k2_pass<false, true>),  dim3(1024), dim3(512), 0, stream, x, ws, d_out);
    hipLaunchKernelGGL((k3_finalize<true>),  dim3(1), dim3(128), 0, stream, gamma, beta, ws);
    hipLaunchKernelGGL((k3_finalize<false>), dim3(1), dim3(128), 0, stream, gamma, beta, ws);
    // output pass (recompute z, fused BN+ReLU)
    hipLaunchKernelGGL((k2_pass<true,  false>), dim3(1024), dim3(512), 0, stream, x, ws, d_out);
    hipLaunchKernelGGL((k2_pass<false, false>), dim3(1024), dim3(512), 0, stream, x, ws, d_out);
}